// Round 5
// baseline (6709.295 us; speedup 1.0000x reference)
//
#include <hip/hip_runtime.h>

#define D_IN 8
#define D_MODEL 1024
#define DEPTH 12
#define D_INNER 2048
#define D_STATE 16
#define D_CONV 4
#define DT_RANK 64
#define BATCH 512

typedef unsigned short ushort_t;
typedef unsigned int uint_t;
typedef __attribute__((ext_vector_type(8))) short short8;
typedef __attribute__((ext_vector_type(16))) float f32x16;

__device__ __forceinline__ float sigmoidf_(float x) { return 1.f / (1.f + expf(-x)); }
__device__ __forceinline__ float siluf_(float x) { return x * sigmoidf_(x); }
__device__ __forceinline__ float softplusf_(float x) { return fmaxf(x, 0.f) + log1pf(expf(-fabsf(x))); }

__device__ __forceinline__ float waveRedSum(float v) {
#pragma unroll
  for (int off = 32; off; off >>= 1) v += __shfl_xor(v, off);
  return v;
}

// ---- bf16 3-way split helpers (RNE) ----
__device__ __forceinline__ ushort_t f2bf(float x) {
  uint_t u = __float_as_uint(x);
  u += 0x7fffu + ((u >> 16) & 1u);
  return (ushort_t)(u >> 16);
}
__device__ __forceinline__ float bf2f(ushort_t h) { return __uint_as_float((uint_t)h << 16); }
__device__ __forceinline__ void split3(float x, ushort_t& s0, ushort_t& s1, ushort_t& s2) {
  s0 = f2bf(x); float r = x - bf2f(s0);
  s1 = f2bf(r); r -= bf2f(s1);
  s2 = f2bf(r);
}
__device__ __forceinline__ uint4 pack8(const ushort_t* u) {
  uint4 v;
  v.x = (uint_t)u[0] | ((uint_t)u[1] << 16);
  v.y = (uint_t)u[2] | ((uint_t)u[3] << 16);
  v.z = (uint_t)u[4] | ((uint_t)u[5] << 16);
  v.w = (uint_t)u[6] | ((uint_t)u[7] << 16);
  return v;
}

// swizzled LDS offset (ushort units). Row = 64 bf16 = 128B; kb = BYTE offset in row.
__device__ __forceinline__ int lds_off(int row, int kb) {
  return row * 64 + ((kb ^ ((row & 7) << 4)) >> 1);
}

// ---- device-scope grid barrier (monotonic counter; counter zeroed per launch) ----
__device__ __forceinline__ void gridBarrier(uint_t* cnt, uint_t target) {
  __syncthreads();
  if (threadIdx.x == 0) {
    __threadfence();
    __hip_atomic_fetch_add(cnt, 1u, __ATOMIC_ACQ_REL, __HIP_MEMORY_SCOPE_AGENT);
    while (__hip_atomic_load(cnt, __ATOMIC_ACQUIRE, __HIP_MEMORY_SCOPE_AGENT) < target) {
      __builtin_amdgcn_s_sleep(2);
    }
  }
  __syncthreads();
}

// ---- weight pre-split: fp32 plane -> 3 bf16 planes ----
__global__ __launch_bounds__(256) void k_presplit(const float* __restrict__ W,
    ushort_t* __restrict__ p0, ushort_t* __restrict__ p1, ushort_t* __restrict__ p2, int n8) {
  for (int i = blockIdx.x * 256 + threadIdx.x; i < n8; i += gridDim.x * 256) {
    const float* g = W + (size_t)i * 8;
    float fv[8];
    *(float4*)&fv[0] = *(const float4*)(g + 0);
    *(float4*)&fv[4] = *(const float4*)(g + 4);
    ushort_t u0[8], u1[8], u2[8];
#pragma unroll
    for (int j = 0; j < 8; ++j) split3(fv[j], u0[j], u1[j], u2[j]);
    ((uint4*)p0)[i] = pack8(u0);
    ((uint4*)p1)[i] = pack8(u1);
    ((uint4*)p2)[i] = pack8(u2);
  }
}

// h[b,m] = x_t[b,:] . Win[m,:] + bin[m]  -> bf16 3-split
__global__ __launch_bounds__(256) void k_input_proj(const float* __restrict__ xt,
    const float* __restrict__ Win, const float* __restrict__ bin,
    ushort_t* __restrict__ h0, ushort_t* __restrict__ h1, ushort_t* __restrict__ h2) {
  int idx = blockIdx.x * 256 + threadIdx.x;
  int b = idx >> 10, m = idx & 1023;
  float acc = bin[m];
  const float* xr = xt + b * D_IN;
  const float* wr = Win + m * D_IN;
#pragma unroll
  for (int k = 0; k < D_IN; ++k) acc += xr[k] * wr[k];
  ushort_t s0, s1, s2; split3(acc, s0, s1, s2);
  h0[idx] = s0; h1[idx] = s1; h2[idx] = s2;
}

// ---- GEMM phase (device fn): identical math to round-3 k_gemm6 ----
template <int MBLK, int NBLK, int KSPLIT, int KLEN>
__device__ void gemm_phase(
    const ushort_t* __restrict__ a0, const ushort_t* __restrict__ a1, const ushort_t* __restrict__ a2,
    const ushort_t* __restrict__ b0, const ushort_t* __restrict__ b1, const ushort_t* __restrict__ b2,
    float* __restrict__ P, int N, int K, ushort_t* lds) {
  constexpr int A_SZ = 64 * 64, B_SZ = 128 * 64;
  ushort_t* Asl = lds;
  ushort_t* Bsl = lds + 3 * A_SZ;

  const int t = threadIdx.x, lane = t & 63, w = t >> 6;
  const int wm = w >> 1;   // n-group (0,1)
  const int ks = w & 1;    // k-chunk slice (0,1)

  constexpr int GRID = MBLK * NBLK * KSPLIT;
  const int id = blockIdx.x;
  const int swz = (id & 7) * (GRID >> 3) + (id >> 3);
  const int kb = swz / (MBLK * NBLK);
  const int r2 = swz % (MBLK * NBLK);
  const int m0 = (r2 % MBLK) * 64, n0 = (r2 / MBLK) * 128;
  const size_t kbase0 = (size_t)kb * KLEN;

  f32x16 acc[2][2];
#pragma unroll
  for (int i = 0; i < 2; ++i)
#pragma unroll
    for (int j = 0; j < 2; ++j)
#pragma unroll
      for (int r = 0; r < 16; ++r) acc[i][j][r] = 0.f;

  const int rA = t >> 2, slA = (t & 3) * 2;
  const int rB = t >> 1, slB = (t & 1) * 4;
  const ushort_t* APL[3] = {a0, a1, a2};
  const ushort_t* BPL[3] = {b0, b1, b2};

  for (int step = 0; step < KLEN / 64; ++step) {
    const size_t kofs = kbase0 + step * 64;
    __syncthreads();
#pragma unroll
    for (int s = 0; s < 3; ++s) {
      const ushort_t* ga = APL[s] + (size_t)(m0 + rA) * K + kofs + slA * 8;
      uint4 v0 = *(const uint4*)ga;
      uint4 v1 = *(const uint4*)(ga + 8);
      *(uint4*)&Asl[s * A_SZ + lds_off(rA, slA * 16)]      = v0;
      *(uint4*)&Asl[s * A_SZ + lds_off(rA, slA * 16 + 16)] = v1;
    }
#pragma unroll
    for (int s = 0; s < 3; ++s) {
      const ushort_t* gb = BPL[s] + (size_t)(n0 + rB) * K + kofs + slB * 8;
      uint4 u0 = *(const uint4*)(gb + 0);
      uint4 u1 = *(const uint4*)(gb + 8);
      uint4 u2 = *(const uint4*)(gb + 16);
      uint4 u3 = *(const uint4*)(gb + 24);
      *(uint4*)&Bsl[s * B_SZ + lds_off(rB, (slB + 0) * 16)] = u0;
      *(uint4*)&Bsl[s * B_SZ + lds_off(rB, (slB + 1) * 16)] = u1;
      *(uint4*)&Bsl[s * B_SZ + lds_off(rB, (slB + 2) * 16)] = u2;
      *(uint4*)&Bsl[s * B_SZ + lds_off(rB, (slB + 3) * 16)] = u3;
    }
    __syncthreads();
#pragma unroll
    for (int cc = 0; cc < 2; ++cc) {
      const int kc = ks * 2 + cc;
      const int kbyte = kc * 32 + (lane >> 5) * 16;
      short8 af[2][3], bf[2][3];
#pragma unroll
      for (int mf = 0; mf < 2; ++mf)
#pragma unroll
        for (int s = 0; s < 3; ++s)
          af[mf][s] = *(const short8*)&Asl[s * A_SZ + lds_off(mf * 32 + (lane & 31), kbyte)];
#pragma unroll
      for (int nf = 0; nf < 2; ++nf)
#pragma unroll
        for (int s = 0; s < 3; ++s)
          bf[nf][s] = *(const short8*)&Bsl[s * B_SZ + lds_off(wm * 64 + nf * 32 + (lane & 31), kbyte)];
#pragma unroll
      for (int mf = 0; mf < 2; ++mf)
#pragma unroll
        for (int nf = 0; nf < 2; ++nf) {
          acc[mf][nf] = __builtin_amdgcn_mfma_f32_32x32x16_bf16(af[mf][0], bf[nf][0], acc[mf][nf], 0, 0, 0);
          acc[mf][nf] = __builtin_amdgcn_mfma_f32_32x32x16_bf16(af[mf][0], bf[nf][1], acc[mf][nf], 0, 0, 0);
          acc[mf][nf] = __builtin_amdgcn_mfma_f32_32x32x16_bf16(af[mf][1], bf[nf][0], acc[mf][nf], 0, 0, 0);
          acc[mf][nf] = __builtin_amdgcn_mfma_f32_32x32x16_bf16(af[mf][1], bf[nf][1], acc[mf][nf], 0, 0, 0);
          acc[mf][nf] = __builtin_amdgcn_mfma_f32_32x32x16_bf16(af[mf][2], bf[nf][0], acc[mf][nf], 0, 0, 0);
          acc[mf][nf] = __builtin_amdgcn_mfma_f32_32x32x16_bf16(af[mf][0], bf[nf][2], acc[mf][nf], 0, 0, 0);
        }
    }
  }

  __syncthreads();
  float* red = (float*)lds;
  const int rbase = (wm * 64 + lane) * 68;
  if (ks == 1) {
#pragma unroll
    for (int j = 0; j < 16; ++j) {
      const int mf = j >> 3, nf = (j >> 2) & 1, r0 = (j & 3) * 4;
      float4 v;
      v.x = acc[mf][nf][r0 + 0]; v.y = acc[mf][nf][r0 + 1];
      v.z = acc[mf][nf][r0 + 2]; v.w = acc[mf][nf][r0 + 3];
      *(float4*)&red[rbase + j * 4] = v;
    }
  }
  __syncthreads();
  if (ks == 0) {
#pragma unroll
    for (int j = 0; j < 16; ++j) {
      const int mf = j >> 3, nf = (j >> 2) & 1, r0 = (j & 3) * 4;
      float4 v = *(const float4*)&red[rbase + j * 4];
      acc[mf][nf][r0 + 0] += v.x; acc[mf][nf][r0 + 1] += v.y;
      acc[mf][nf][r0 + 2] += v.z; acc[mf][nf][r0 + 3] += v.w;
    }
    float* Pk = P + (size_t)kb * 512 * N;
#pragma unroll
    for (int mf = 0; mf < 2; ++mf) {
      const int n = n0 + wm * 64 + (lane & 31);
#pragma unroll
      for (int nf = 0; nf < 2; ++nf)
#pragma unroll
        for (int r = 0; r < 16; ++r) {
          const int m = m0 + mf * 32 + (r & 3) + 8 * (r >> 2) + 4 * (lane >> 5);
          Pk[(size_t)m * N + n + nf * 32] = acc[mf][nf][r];
        }
    }
  }
}

// ---- fused phase: 2 batch rows per block (256 blocks) ----
__device__ void fused_phase(
    const float* __restrict__ xz,
    const float* __restrict__ cst, const float* __restrict__ sst,
    const float* __restrict__ cw, const float* __restrict__ cb,
    const float* __restrict__ xpw, const float* __restrict__ dtw, const float* __restrict__ dtb,
    const float* __restrict__ alog, const float* __restrict__ dpar,
    ushort_t* __restrict__ y0, ushort_t* __restrict__ y1, ushort_t* __restrict__ y2,
    float* slds) {
  float* sxc0 = slds;          // [2048]
  float* sxc1 = slds + 2048;   // [2048]
  float* sxdb = slds + 4096;   // [2][96]
  const int t = threadIdx.x;
  const int b0 = blockIdx.x * 2;

#pragma unroll
  for (int bb = 0; bb < 2; ++bb) {
    const int b = b0 + bb;
    float* sxc = bb ? sxc1 : sxc0;
    for (int d = t; d < D_INNER; d += 256) {
      float4 c = *(const float4*)&cst[((size_t)b * D_INNER + d) * 4];
      float4 w = *(const float4*)&cw[d * 4];
      const size_t xi = (size_t)b * 4096 + d;
      float xv = xz[xi];
      float a = c.y * w.x + c.z * w.y + c.w * w.z + xv * w.w + cb[d];
      sxc[d] = siluf_(a);
    }
  }
  __syncthreads();

  const int wave = t >> 6, lane = t & 63;
  for (int r = wave * 24; r < wave * 24 + 24; ++r) {
    float a0 = 0.f, a1 = 0.f;
    const float* wr = &xpw[(size_t)r * D_INNER];
    for (int k = lane; k < D_INNER; k += 64) {
      float wv = wr[k];
      a0 += wv * sxc0[k];
      a1 += wv * sxc1[k];
    }
    a0 = waveRedSum(a0);
    a1 = waveRedSum(a1);
    if (lane == 0) { sxdb[r] = a0; sxdb[96 + r] = a1; }
  }
  __syncthreads();

  for (int d = t; d < D_INNER; d += 256) {
    float An[D_STATE];
#pragma unroll
    for (int n = 0; n < D_STATE; ++n) An[n] = -expf(alog[(size_t)d * D_STATE + n]);
    float dtwv[DT_RANK];
#pragma unroll
    for (int j4 = 0; j4 < DT_RANK / 4; ++j4)
      *(float4*)&dtwv[j4 * 4] = *(const float4*)&dtw[(size_t)d * DT_RANK + j4 * 4];
    const float dtbv = dtb[d], dp = dpar[d];
#pragma unroll
    for (int bb = 0; bb < 2; ++bb) {
      const int b = b0 + bb;
      const float* sx = bb ? sxc1 : sxc0;
      const float* sdb = sxdb + bb * 96;
      float dtr = dtbv;
#pragma unroll
      for (int j = 0; j < DT_RANK; ++j) dtr += sdb[j] * dtwv[j];
      float dtv = softplusf_(dtr);
      float xcv = sx[d];
      float dx = dtv * xcv;
      const float* srow = &sst[((size_t)b * D_INNER + d) * D_STATE];
      float acc = 0.f;
#pragma unroll
      for (int n = 0; n < D_STATE; ++n) {
        float Bn = sdb[DT_RANK + n];
        float Cn = sdb[DT_RANK + D_STATE + n];
        float sNew = srow[n] * expf(dtv * An[n]) + dx * Bn;
        acc += sNew * Cn;
      }
      float yv = acc + dp * xcv;
      const size_t zi = (size_t)b * 4096 + D_INNER + d;
      float zv = xz[zi];
      yv *= siluf_(zv);
      ushort_t s0, s1, s2; split3(yv, s0, s1, s2);
      const size_t off = (size_t)b * D_INNER + d;
      y0[off] = s0; y1[off] = s1; y2[off] = s2;
    }
  }
}

// ---- reduce phase: h = sum of 4 out_proj partials + h bf16 splits ----
__device__ void reduce_phase(const float* __restrict__ P, float* __restrict__ h,
    ushort_t* __restrict__ h0, ushort_t* __restrict__ h1, ushort_t* __restrict__ h2) {
#pragma unroll
  for (int it = 0; it < 2; ++it) {
    const int i = it * 65536 + blockIdx.x * 256 + threadIdx.x;  // 131072 float4 total
    float4 a = ((const float4*)P)[i];
#pragma unroll
    for (int p = 1; p < 4; ++p) {
      float4 b = ((const float4*)P)[(size_t)p * 131072 + i];
      a.x += b.x; a.y += b.y; a.z += b.z; a.w += b.w;
    }
    ((float4*)h)[i] = a;
    float fv[4] = {a.x, a.y, a.z, a.w};
    ushort_t u0[4], u1[4], u2[4];
#pragma unroll
    for (int j = 0; j < 4; ++j) split3(fv[j], u0[j], u1[j], u2[j]);
    ((uint2*)h0)[i] = make_uint2((uint_t)u0[0] | ((uint_t)u0[1] << 16), (uint_t)u0[2] | ((uint_t)u0[3] << 16));
    ((uint2*)h1)[i] = make_uint2((uint_t)u1[0] | ((uint_t)u1[1] << 16), (uint_t)u1[2] | ((uint_t)u1[3] << 16));
    ((uint2*)h2)[i] = make_uint2((uint_t)u2[0] | ((uint_t)u2[1] << 16), (uint_t)u2[2] | ((uint_t)u2[3] << 16));
  }
}

struct MegaArgs {
  ushort_t *h0, *h1, *h2;
  ushort_t *y0, *y1, *y2;
  const ushort_t *iw0, *iw1, *iw2;
  const ushort_t *ow0, *ow1, *ow2;
  const float *cst, *sst, *cw, *cb, *xpw, *dtw, *dtb, *alog, *dpar;
  float *xz, *Pout, *h;
  uint_t* cnt;
};

// All 12 layers in one launch; 256 blocks (1/CU guaranteed resident -> barrier safe).
__global__ __launch_bounds__(256, 2) void k_mega(MegaArgs a) {
  __shared__ __align__(16) ushort_t lds[36864];  // 73728 B
  uint_t bar = 0;

  for (int l = 0; l < DEPTH; ++l) {
    // in_proj: xz[512][4096] = h . ipw^T  (8x32 tiles, no split-K)
    gemm_phase<8, 32, 1, 1024>(a.h0, a.h1, a.h2,
        a.iw0 + (size_t)l * 4194304, a.iw1 + (size_t)l * 4194304, a.iw2 + (size_t)l * 4194304,
        a.xz, 4096, 1024, lds);
    gridBarrier(a.cnt, (++bar) * 256);

    fused_phase(a.xz,
        a.cst + (size_t)l * BATCH * D_INNER * D_CONV,
        a.sst + (size_t)l * BATCH * D_INNER * D_STATE,
        a.cw + (size_t)l * D_INNER * D_CONV, a.cb + (size_t)l * D_INNER,
        a.xpw + (size_t)l * 96 * D_INNER,
        a.dtw + (size_t)l * D_INNER * DT_RANK, a.dtb + (size_t)l * D_INNER,
        a.alog + (size_t)l * D_INNER * D_STATE, a.dpar + (size_t)l * D_INNER,
        a.y0, a.y1, a.y2, (float*)lds);
    gridBarrier(a.cnt, (++bar) * 256);

    // out_proj: Pout[4][512][1024] = y . opw^T  (8x8 tiles x KSPLIT=4)
    gemm_phase<8, 8, 4, 512>(a.y0, a.y1, a.y2,
        a.ow0 + (size_t)l * 2097152, a.ow1 + (size_t)l * 2097152, a.ow2 + (size_t)l * 2097152,
        a.Pout, 1024, 2048, lds);
    gridBarrier(a.cnt, (++bar) * 256);

    reduce_phase(a.Pout, a.h, a.h0, a.h1, a.h2);
    gridBarrier(a.cnt, (++bar) * 256);
  }
}

__global__ __launch_bounds__(256) void k_layernorm(const float* __restrict__ h,
    const float* __restrict__ lnw, const float* __restrict__ lnb, float* __restrict__ out) {
  __shared__ float red[4];
  const int b = blockIdx.x, t = threadIdx.x;
  const float* row = h + (size_t)b * D_MODEL;
  float4 x = *(const float4*)&row[t * 4];
  float s = x.x + x.y + x.z + x.w;
  s = waveRedSum(s);
  const int wave = t >> 6, lane = t & 63;
  if (lane == 0) red[wave] = s;
  __syncthreads();
  float mu = (red[0] + red[1] + red[2] + red[3]) * (1.f / 1024.f);
  float d0 = x.x - mu, d1 = x.y - mu, d2 = x.z - mu, d3 = x.w - mu;
  float q = d0 * d0 + d1 * d1 + d2 * d2 + d3 * d3;
  q = waveRedSum(q);
  __syncthreads();
  if (lane == 0) red[wave] = q;
  __syncthreads();
  float var = (red[0] + red[1] + red[2] + red[3]) * (1.f / 1024.f);
  float inv = 1.f / sqrtf(var + 1e-5f);
  float4 wv = *(const float4*)&lnw[t * 4];
  float4 bv = *(const float4*)&lnb[t * 4];
  float4 o;
  o.x = d0 * inv * wv.x + bv.x;
  o.y = d1 * inv * wv.y + bv.y;
  o.z = d2 * inv * wv.z + bv.z;
  o.w = d3 * inv * wv.w + bv.w;
  *(float4*)&out[(size_t)b * D_MODEL + t * 4] = o;
}

extern "C" void kernel_launch(void* const* d_in, const int* in_sizes, int n_in,
                              void* d_out, int out_size, void* d_ws, size_t ws_size,
                              hipStream_t stream) {
  const float* x_t  = (const float*)d_in[0];
  const float* cst  = (const float*)d_in[1];
  const float* sst  = (const float*)d_in[2];
  const float* Win  = (const float*)d_in[3];
  const float* bin  = (const float*)d_in[4];
  const float* ipw  = (const float*)d_in[5];
  const float* cw   = (const float*)d_in[6];
  const float* cb   = (const float*)d_in[7];
  const float* xpw  = (const float*)d_in[8];
  const float* dtw  = (const float*)d_in[9];
  const float* dtb  = (const float*)d_in[10];
  const float* alog = (const float*)d_in[11];
  const float* dpar = (const float*)d_in[12];
  const float* opw  = (const float*)d_in[13];
  const float* lnw  = (const float*)d_in[14];
  const float* lnb  = (const float*)d_in[15];

  float* ws   = (float*)d_ws;
  float* h    = ws;                        // 524288 f32
  float* xz   = h + 524288;                // 2097152 f32
  float* Pout = xz + 2097152;              // 4 x 524288 f32
  uint_t* barcnt = (uint_t*)(Pout + 2097152);   // 64 uints
  ushort_t* u = (ushort_t*)(barcnt + 64);
  ushort_t* h0 = u;              ushort_t* h1 = h0 + 524288;   ushort_t* h2 = h1 + 524288;
  ushort_t* y0 = h2 + 524288;    ushort_t* y1 = y0 + 1048576;  ushort_t* y2 = y1 + 1048576;
  ushort_t* iw0 = y2 + 1048576;
  ushort_t* iw1 = iw0 + 50331648;
  ushort_t* iw2 = iw1 + 50331648;
  ushort_t* ow0 = iw2 + 50331648;
  ushort_t* ow1 = ow0 + 25165824;
  ushort_t* ow2 = ow1 + 25165824;

  k_presplit<<<2048, 256, 0, stream>>>(ipw, iw0, iw1, iw2, 6291456);
  k_presplit<<<2048, 256, 0, stream>>>(opw, ow0, ow1, ow2, 3145728);
  k_input_proj<<<2048, 256, 0, stream>>>(x_t, Win, bin, h0, h1, h2);
  hipMemsetAsync(barcnt, 0, 256, stream);

  MegaArgs ma;
  ma.h0 = h0; ma.h1 = h1; ma.h2 = h2;
  ma.y0 = y0; ma.y1 = y1; ma.y2 = y2;
  ma.iw0 = iw0; ma.iw1 = iw1; ma.iw2 = iw2;
  ma.ow0 = ow0; ma.ow1 = ow1; ma.ow2 = ow2;
  ma.cst = cst; ma.sst = sst; ma.cw = cw; ma.cb = cb; ma.xpw = xpw;
  ma.dtw = dtw; ma.dtb = dtb; ma.alog = alog; ma.dpar = dpar;
  ma.xz = xz; ma.Pout = Pout; ma.h = h;
  ma.cnt = barcnt;

  k_mega<<<256, 256, 0, stream>>>(ma);

  k_layernorm<<<512, 256, 0, stream>>>(h, lnw, lnb, (float*)d_out);
}

// Round 6
// 2574.985 us; speedup vs baseline: 2.6056x; 2.6056x over previous
//
#include <hip/hip_runtime.h>

#define D_IN 8
#define D_MODEL 1024
#define DEPTH 12
#define D_INNER 2048
#define D_STATE 16
#define D_CONV 4
#define DT_RANK 64
#define BATCH 512

typedef unsigned short ushort_t;
typedef unsigned int uint_t;
typedef __attribute__((ext_vector_type(8))) short short8;
typedef __attribute__((ext_vector_type(16))) float f32x16;

__device__ __forceinline__ float sigmoidf_(float x) { return 1.f / (1.f + expf(-x)); }
__device__ __forceinline__ float siluf_(float x) { return x * sigmoidf_(x); }
__device__ __forceinline__ float softplusf_(float x) { return fmaxf(x, 0.f) + log1pf(expf(-fabsf(x))); }

__device__ __forceinline__ float waveRedSum(float v) {
#pragma unroll
  for (int off = 32; off; off >>= 1) v += __shfl_xor(v, off);
  return v;
}

// ---- bf16 3-way split helpers (RNE) ----
__device__ __forceinline__ ushort_t f2bf(float x) {
  uint_t u = __float_as_uint(x);
  u += 0x7fffu + ((u >> 16) & 1u);
  return (ushort_t)(u >> 16);
}
__device__ __forceinline__ float bf2f(ushort_t h) { return __uint_as_float((uint_t)h << 16); }
__device__ __forceinline__ void split3(float x, ushort_t& s0, ushort_t& s1, ushort_t& s2) {
  s0 = f2bf(x); float r = x - bf2f(s0);
  s1 = f2bf(r); r -= bf2f(s1);
  s2 = f2bf(r);
}
__device__ __forceinline__ uint4 pack8(const ushort_t* u) {
  uint4 v;
  v.x = (uint_t)u[0] | ((uint_t)u[1] << 16);
  v.y = (uint_t)u[2] | ((uint_t)u[3] << 16);
  v.z = (uint_t)u[4] | ((uint_t)u[5] << 16);
  v.w = (uint_t)u[6] | ((uint_t)u[7] << 16);
  return v;
}

// LDS offset (ushort units) for 32-ushort (64B) rows, 4x16B slots, XOR(row&3) spread.
__device__ __forceinline__ int off32(int row, int kb) {
  return row * 32 + ((kb ^ ((row & 3) << 4)) >> 1);
}

// ---- weight pre-split: fp32 plane -> 3 bf16 planes ----
__global__ __launch_bounds__(256) void k_presplit(const float* __restrict__ W,
    ushort_t* __restrict__ p0, ushort_t* __restrict__ p1, ushort_t* __restrict__ p2, int n8) {
  for (int i = blockIdx.x * 256 + threadIdx.x; i < n8; i += gridDim.x * 256) {
    const float* g = W + (size_t)i * 8;
    float fv[8];
    *(float4*)&fv[0] = *(const float4*)(g + 0);
    *(float4*)&fv[4] = *(const float4*)(g + 4);
    ushort_t u0[8], u1[8], u2[8];
#pragma unroll
    for (int j = 0; j < 8; ++j) split3(fv[j], u0[j], u1[j], u2[j]);
    ((uint4*)p0)[i] = pack8(u0);
    ((uint4*)p1)[i] = pack8(u1);
    ((uint4*)p2)[i] = pack8(u2);
  }
}

// h[b,m] = x_t[b,:] . Win[m,:] + bin[m]  -> bf16 3-split
__global__ __launch_bounds__(256) void k_input_proj(const float* __restrict__ xt,
    const float* __restrict__ Win, const float* __restrict__ bin,
    ushort_t* __restrict__ h0, ushort_t* __restrict__ h1, ushort_t* __restrict__ h2) {
  int idx = blockIdx.x * 256 + threadIdx.x;
  int b = idx >> 10, m = idx & 1023;
  float acc = bin[m];
  const float* xr = xt + b * D_IN;
  const float* wr = Win + m * D_IN;
#pragma unroll
  for (int k = 0; k < D_IN; ++k) acc += xr[k] * wr[k];
  ushort_t s0, s1, s2; split3(acc, s0, s1, s2);
  h0[idx] = s0; h1[idx] = s1; h2[idx] = s2;
}

// P_partial[kb] = A . B^T over k-slice. Tiles 64m x 128n, BK=32, 4 waves
// (2 n-groups x 2 k-chunks). LDS 36 KB -> 4 blocks/CU; VGPR capped at 128
// via launch_bounds(256,4) -> 16 waves/CU.
template <int MBLK, int NBLK, int KSPLIT, int KLEN>
__global__ __launch_bounds__(256, 4) void k_gemm6(
    const ushort_t* __restrict__ a0, const ushort_t* __restrict__ a1, const ushort_t* __restrict__ a2,
    const ushort_t* __restrict__ b0, const ushort_t* __restrict__ b1, const ushort_t* __restrict__ b2,
    float* __restrict__ P, int N, int K) {
  constexpr int A_SZ = 64 * 32, B_SZ = 128 * 32;     // ushorts per split plane
  __shared__ ushort_t lds[3 * A_SZ + 3 * B_SZ];      // 36864 B
  ushort_t* Asl = lds;
  ushort_t* Bsl = lds + 3 * A_SZ;

  const int t = threadIdx.x, lane = t & 63, w = t >> 6;
  const int wm = w >> 1;   // n-group (0,1)
  const int ks = w & 1;    // k16-chunk (0,1)

  constexpr int GRID = MBLK * NBLK * KSPLIT;
  const int id = blockIdx.x;
  const int swz = (id & 7) * (GRID >> 3) + (id >> 3);
  const int kb = swz / (MBLK * NBLK);
  const int r2 = swz % (MBLK * NBLK);
  const int m0 = (r2 % MBLK) * 64, n0 = (r2 / MBLK) * 128;
  const size_t kbase0 = (size_t)kb * KLEN;

  f32x16 acc[2][2];
#pragma unroll
  for (int i = 0; i < 2; ++i)
#pragma unroll
    for (int j = 0; j < 2; ++j)
#pragma unroll
      for (int r = 0; r < 16; ++r) acc[i][j][r] = 0.f;

  const int rA = t >> 2, sl = t & 3;  // A: 64 rows x 4 slots; B uses rA and rA+64
  const ushort_t* APL[3] = {a0, a1, a2};
  const ushort_t* BPL[3] = {b0, b1, b2};

  for (int step = 0; step < KLEN / 32; ++step) {
    const size_t kofs = kbase0 + step * 32;
    __syncthreads();
#pragma unroll
    for (int s = 0; s < 3; ++s) {
      const ushort_t* ga = APL[s] + (size_t)(m0 + rA) * K + kofs + sl * 8;
      *(uint4*)&Asl[s * A_SZ + off32(rA, sl * 16)] = *(const uint4*)ga;
    }
#pragma unroll
    for (int j = 0; j < 2; ++j) {
      const int rB = rA + j * 64;
#pragma unroll
      for (int s = 0; s < 3; ++s) {
        const ushort_t* gb = BPL[s] + (size_t)(n0 + rB) * K + kofs + sl * 8;
        *(uint4*)&Bsl[s * B_SZ + off32(rB, sl * 16)] = *(const uint4*)gb;
      }
    }
    __syncthreads();
    const int kbyte = ks * 32 + (lane >> 5) * 16;
    short8 af[2][3], bf[2][3];
#pragma unroll
    for (int mf = 0; mf < 2; ++mf)
#pragma unroll
      for (int s = 0; s < 3; ++s)
        af[mf][s] = *(const short8*)&Asl[s * A_SZ + off32(mf * 32 + (lane & 31), kbyte)];
#pragma unroll
    for (int nf = 0; nf < 2; ++nf)
#pragma unroll
      for (int s = 0; s < 3; ++s)
        bf[nf][s] = *(const short8*)&Bsl[s * B_SZ + off32(wm * 64 + nf * 32 + (lane & 31), kbyte)];
#pragma unroll
    for (int mf = 0; mf < 2; ++mf)
#pragma unroll
      for (int nf = 0; nf < 2; ++nf) {
        acc[mf][nf] = __builtin_amdgcn_mfma_f32_32x32x16_bf16(af[mf][0], bf[nf][0], acc[mf][nf], 0, 0, 0);
        acc[mf][nf] = __builtin_amdgcn_mfma_f32_32x32x16_bf16(af[mf][0], bf[nf][1], acc[mf][nf], 0, 0, 0);
        acc[mf][nf] = __builtin_amdgcn_mfma_f32_32x32x16_bf16(af[mf][1], bf[nf][0], acc[mf][nf], 0, 0, 0);
        acc[mf][nf] = __builtin_amdgcn_mfma_f32_32x32x16_bf16(af[mf][1], bf[nf][1], acc[mf][nf], 0, 0, 0);
        acc[mf][nf] = __builtin_amdgcn_mfma_f32_32x32x16_bf16(af[mf][2], bf[nf][0], acc[mf][nf], 0, 0, 0);
        acc[mf][nf] = __builtin_amdgcn_mfma_f32_32x32x16_bf16(af[mf][0], bf[nf][2], acc[mf][nf], 0, 0, 0);
      }
  }

  // in-block reduce of the 2 k-chunks (ks=1 -> ks=0), then write partial tile
  __syncthreads();
  float* red = (float*)lds;
  const int rbase = (wm * 64 + lane) * 68;   // 128*68*4 = 34816 B <= 36864
  if (ks == 1) {
#pragma unroll
    for (int j = 0; j < 16; ++j) {
      const int mf = j >> 3, nf = (j >> 2) & 1, r0 = (j & 3) * 4;
      float4 v;
      v.x = acc[mf][nf][r0 + 0]; v.y = acc[mf][nf][r0 + 1];
      v.z = acc[mf][nf][r0 + 2]; v.w = acc[mf][nf][r0 + 3];
      *(float4*)&red[rbase + j * 4] = v;
    }
  }
  __syncthreads();
  if (ks == 0) {
#pragma unroll
    for (int j = 0; j < 16; ++j) {
      const int mf = j >> 3, nf = (j >> 2) & 1, r0 = (j & 3) * 4;
      float4 v = *(const float4*)&red[rbase + j * 4];
      acc[mf][nf][r0 + 0] += v.x; acc[mf][nf][r0 + 1] += v.y;
      acc[mf][nf][r0 + 2] += v.z; acc[mf][nf][r0 + 3] += v.w;
    }
    float* Pk = P + (size_t)kb * 512 * N;
#pragma unroll
    for (int mf = 0; mf < 2; ++mf) {
      const int n = n0 + wm * 64 + (lane & 31);
#pragma unroll
      for (int nf = 0; nf < 2; ++nf)
#pragma unroll
        for (int r = 0; r < 16; ++r) {
          const int m = m0 + mf * 32 + (r & 3) + 8 * (r >> 2) + 4 * (lane >> 5);
          Pk[(size_t)m * N + n + nf * 32] = acc[mf][nf][r];
        }
    }
  }
}

// Fused: (sum 4 Pin partials) conv1d+SiLU -> x_proj -> dt_proj+softplus -> SSM -> gate.
// 1 batch row per block, 512 blocks.
__global__ __launch_bounds__(256) void k_fused(
    const float* __restrict__ Pin,   // [4][512][4096]
    const float* __restrict__ cst, const float* __restrict__ sst,
    const float* __restrict__ cw, const float* __restrict__ cb,
    const float* __restrict__ xpw, const float* __restrict__ dtw, const float* __restrict__ dtb,
    const float* __restrict__ alog, const float* __restrict__ dpar,
    ushort_t* __restrict__ y0, ushort_t* __restrict__ y1, ushort_t* __restrict__ y2) {
  __shared__ float sxc[D_INNER];
  __shared__ float sxdb[96];
  const int t = threadIdx.x;
  const int b = blockIdx.x;
  const size_t S = 2097152;

  for (int d = t; d < D_INNER; d += 256) {
    float4 c = *(const float4*)&cst[((size_t)b * D_INNER + d) * 4];
    float4 w = *(const float4*)&cw[d * 4];
    const size_t xi = (size_t)b * 4096 + d;
    float xv = Pin[xi] + Pin[xi + S] + Pin[xi + 2 * S] + Pin[xi + 3 * S];
    float a = c.y * w.x + c.z * w.y + c.w * w.z + xv * w.w + cb[d];
    sxc[d] = siluf_(a);
  }
  __syncthreads();

  const int wave = t >> 6, lane = t & 63;
  for (int r = wave * 24; r < wave * 24 + 24; ++r) {
    const float* wr = &xpw[(size_t)r * D_INNER];
    float p0 = 0.f, p1 = 0.f, p2 = 0.f, p3 = 0.f;
    for (int k = lane; k < D_INNER; k += 256) {
      p0 += wr[k] * sxc[k];
      p1 += wr[k + 64] * sxc[k + 64];
      p2 += wr[k + 128] * sxc[k + 128];
      p3 += wr[k + 192] * sxc[k + 192];
    }
    float a = waveRedSum((p0 + p1) + (p2 + p3));
    if (lane == 0) sxdb[r] = a;
  }
  __syncthreads();

  for (int d = t; d < D_INNER; d += 256) {
    float An[D_STATE];
#pragma unroll
    for (int n = 0; n < D_STATE; ++n) An[n] = -expf(alog[(size_t)d * D_STATE + n]);
    float dtr = dtb[d];
#pragma unroll
    for (int j4 = 0; j4 < DT_RANK / 4; ++j4) {
      float4 wv = *(const float4*)&dtw[(size_t)d * DT_RANK + j4 * 4];
      dtr += sxdb[j4 * 4] * wv.x + sxdb[j4 * 4 + 1] * wv.y +
             sxdb[j4 * 4 + 2] * wv.z + sxdb[j4 * 4 + 3] * wv.w;
    }
    float dtv = softplusf_(dtr);
    float xcv = sxc[d];
    float dx = dtv * xcv;
    const float* srow = &sst[((size_t)b * D_INNER + d) * D_STATE];
    float acc = 0.f;
#pragma unroll
    for (int n = 0; n < D_STATE; ++n) {
      float Bn = sxdb[DT_RANK + n];
      float Cn = sxdb[DT_RANK + D_STATE + n];
      float sNew = srow[n] * expf(dtv * An[n]) + dx * Bn;
      acc += sNew * Cn;
    }
    float yv = acc + dpar[d] * xcv;
    const size_t zi = (size_t)b * 4096 + D_INNER + d;
    float zv = Pin[zi] + Pin[zi + S] + Pin[zi + 2 * S] + Pin[zi + 3 * S];
    yv *= siluf_(zv);
    ushort_t s0, s1, s2; split3(yv, s0, s1, s2);
    const size_t off = (size_t)b * D_INNER + d;
    y0[off] = s0; y1[off] = s1; y2[off] = s2;
  }
}

// h = sum of 16 out_proj partials; also emit h bf16 3-splits for next layer
__global__ __launch_bounds__(256) void k_reduce_out(const float* __restrict__ P,
    float* __restrict__ h, ushort_t* __restrict__ h0, ushort_t* __restrict__ h1,
    ushort_t* __restrict__ h2) {
  const int i = blockIdx.x * 256 + threadIdx.x;  // 131072 float4
  float4 a = ((const float4*)P)[i];
#pragma unroll
  for (int p = 1; p < 16; ++p) {
    float4 b = ((const float4*)P)[(size_t)p * 131072 + i];
    a.x += b.x; a.y += b.y; a.z += b.z; a.w += b.w;
  }
  ((float4*)h)[i] = a;
  float fv[4] = {a.x, a.y, a.z, a.w};
  ushort_t u0[4], u1[4], u2[4];
#pragma unroll
  for (int j = 0; j < 4; ++j) split3(fv[j], u0[j], u1[j], u2[j]);
  ((uint2*)h0)[i] = make_uint2((uint_t)u0[0] | ((uint_t)u0[1] << 16), (uint_t)u0[2] | ((uint_t)u0[3] << 16));
  ((uint2*)h1)[i] = make_uint2((uint_t)u1[0] | ((uint_t)u1[1] << 16), (uint_t)u1[2] | ((uint_t)u1[3] << 16));
  ((uint2*)h2)[i] = make_uint2((uint_t)u2[0] | ((uint_t)u2[1] << 16), (uint_t)u2[2] | ((uint_t)u2[3] << 16));
}

__global__ __launch_bounds__(256) void k_layernorm(const float* __restrict__ h,
    const float* __restrict__ lnw, const float* __restrict__ lnb, float* __restrict__ out) {
  __shared__ float red[4];
  const int b = blockIdx.x, t = threadIdx.x;
  const float* row = h + (size_t)b * D_MODEL;
  float4 x = *(const float4*)&row[t * 4];
  float s = x.x + x.y + x.z + x.w;
  s = waveRedSum(s);
  const int wave = t >> 6, lane = t & 63;
  if (lane == 0) red[wave] = s;
  __syncthreads();
  float mu = (red[0] + red[1] + red[2] + red[3]) * (1.f / 1024.f);
  float d0 = x.x - mu, d1 = x.y - mu, d2 = x.z - mu, d3 = x.w - mu;
  float q = d0 * d0 + d1 * d1 + d2 * d2 + d3 * d3;
  q = waveRedSum(q);
  __syncthreads();
  if (lane == 0) red[wave] = q;
  __syncthreads();
  float var = (red[0] + red[1] + red[2] + red[3]) * (1.f / 1024.f);
  float inv = 1.f / sqrtf(var + 1e-5f);
  float4 wv = *(const float4*)&lnw[t * 4];
  float4 bv = *(const float4*)&lnb[t * 4];
  float4 o;
  o.x = d0 * inv * wv.x + bv.x;
  o.y = d1 * inv * wv.y + bv.y;
  o.z = d2 * inv * wv.z + bv.z;
  o.w = d3 * inv * wv.w + bv.w;
  *(float4*)&out[(size_t)b * D_MODEL + t * 4] = o;
}

extern "C" void kernel_launch(void* const* d_in, const int* in_sizes, int n_in,
                              void* d_out, int out_size, void* d_ws, size_t ws_size,
                              hipStream_t stream) {
  const float* x_t  = (const float*)d_in[0];
  const float* cst  = (const float*)d_in[1];
  const float* sst  = (const float*)d_in[2];
  const float* Win  = (const float*)d_in[3];
  const float* bin  = (const float*)d_in[4];
  const float* ipw  = (const float*)d_in[5];
  const float* cw   = (const float*)d_in[6];
  const float* cb   = (const float*)d_in[7];
  const float* xpw  = (const float*)d_in[8];
  const float* dtw  = (const float*)d_in[9];
  const float* dtb  = (const float*)d_in[10];
  const float* alog = (const float*)d_in[11];
  const float* dpar = (const float*)d_in[12];
  const float* opw  = (const float*)d_in[13];
  const float* lnw  = (const float*)d_in[14];
  const float* lnb  = (const float*)d_in[15];

  float* ws   = (float*)d_ws;
  float* h    = ws;                         // 524288 f32
  float* Pin  = h + 524288;                 // 4 x 2097152 f32
  float* Pout = Pin + 8388608;              // 16 x 524288 f32
  ushort_t* u = (ushort_t*)(Pout + 8388608);
  ushort_t* h0 = u;              ushort_t* h1 = h0 + 524288;   ushort_t* h2 = h1 + 524288;
  ushort_t* y0 = h2 + 524288;    ushort_t* y1 = y0 + 1048576;  ushort_t* y2 = y1 + 1048576;
  ushort_t* iw0 = y2 + 1048576;
  ushort_t* iw1 = iw0 + 50331648;
  ushort_t* iw2 = iw1 + 50331648;
  ushort_t* ow0 = iw2 + 50331648;
  ushort_t* ow1 = ow0 + 25165824;
  ushort_t* ow2 = ow1 + 25165824;

  k_presplit<<<2048, 256, 0, stream>>>(ipw, iw0, iw1, iw2, 6291456);
  k_presplit<<<2048, 256, 0, stream>>>(opw, ow0, ow1, ow2, 3145728);
  k_input_proj<<<2048, 256, 0, stream>>>(x_t, Win, bin, h0, h1, h2);

  for (int l = 0; l < DEPTH; ++l) {
    const size_t iwo = (size_t)l * 4194304;
    const size_t owo = (size_t)l * 2097152;
    // in_proj: Pin[4][512][4096] = h . ipw^T  (8m x 32n x KSPLIT4 = 1024 blocks)
    k_gemm6<8, 32, 4, 256><<<1024, 256, 0, stream>>>(
        h0, h1, h2, iw0 + iwo, iw1 + iwo, iw2 + iwo, Pin, 4096, 1024);
    k_fused<<<512, 256, 0, stream>>>(
        Pin,
        cst + (size_t)l * BATCH * D_INNER * D_CONV,
        sst + (size_t)l * BATCH * D_INNER * D_STATE,
        cw + (size_t)l * D_INNER * D_CONV, cb + (size_t)l * D_INNER,
        xpw + (size_t)l * 96 * D_INNER,
        dtw + (size_t)l * D_INNER * DT_RANK, dtb + (size_t)l * D_INNER,
        alog + (size_t)l * D_INNER * D_STATE, dpar + (size_t)l * D_INNER,
        y0, y1, y2);
    // out_proj: Pout[16][512][1024] = y . opw^T  (8m x 8n x KSPLIT16 = 1024 blocks)
    k_gemm6<8, 8, 16, 128><<<1024, 256, 0, stream>>>(
        y0, y1, y2, ow0 + owo, ow1 + owo, ow2 + owo, Pout, 1024, 2048);
    k_reduce_out<<<512, 256, 0, stream>>>(Pout, h, h0, h1, h2);
  }

  k_layernorm<<<512, 256, 0, stream>>>(h, lnw, lnb, (float*)d_out);
}